// Round 5
// baseline (75.473 us; speedup 1.0000x reference)
//
#include <hip/hip_runtime.h>
#include <hip/hip_fp16.h>

#define B_      8
#define CIN_    256
#define COUT_   256
#define K_      4
#define H_      128
#define W_      128
#define NPTS_   512

#define NPTS_TOT_   (B_ * NPTS_)                 // 4096
#define T_BYTES_    ((size_t)B_ * H_ * W_ * CIN_ * sizeof(__half))   // 67,108,864

// =====================================================================
// K_A: transpose CHW fp32 -> HWC fp16, sequential-read tiles.
// Block = (b, cg, hh): 64 channels x 256 pixels (2 h-rows).
// Read: each wave reads whole channel rows, 1 KB contiguous per instr.
// Write: each thread emits one COMPLETE 128-B line (64 ch fp16) of T.
// grid: 8 * 4 * 64 = 2048 blocks, 256 threads.
// =====================================================================
__global__ __launch_bounds__(256) void ka_kernel(
    const float* __restrict__ input,   // [B, CIN, H, W]
    __half* __restrict__ T)            // [B, H, W, C]
{
    __shared__ unsigned int lt[32][256];   // [c-pair][px], packed half2, 32 KB

    const int bid = blockIdx.x;        // 0..2047
    const int b   = bid >> 8;          // /256
    const int r   = bid & 255;
    const int cg  = r >> 6;            // 0..3  (channel group of 64)
    const int hh  = r & 63;            // 0..63 (h-pair)

    const int t    = threadIdx.x;
    const int wv   = t >> 6;           // 0..3
    const int lane = t & 63;

    // ---- read phase: wave wv owns relative channel pairs wv*8..wv*8+7 ----
    // channel row segment = (h=2hh, w=0..127)+(h=2hh+1, w=0..127) = 256 floats contiguous
    const size_t base = ((size_t)(b * CIN_ + cg * 64) * H_ + 2 * hh) * W_;
    float4 A[8], Bv[8];
    #pragma unroll
    for (int ii = 0; ii < 8; ++ii) {
        const int c = wv * 16 + 2 * ii;            // relative even channel
        const float* rowA = input + base + (size_t)c * (H_ * W_);
        const float* rowB = rowA + (H_ * W_);
        A[ii]  = *reinterpret_cast<const float4*>(rowA + lane * 4);
        Bv[ii] = *reinterpret_cast<const float4*>(rowB + lane * 4);
    }
    #pragma unroll
    for (int ii = 0; ii < 8; ++ii) {
        const int i = wv * 8 + ii;                 // pair row in LDS
        __half2 h0 = __floats2half2_rn(A[ii].x, Bv[ii].x);
        __half2 h1 = __floats2half2_rn(A[ii].y, Bv[ii].y);
        __half2 h2 = __floats2half2_rn(A[ii].z, Bv[ii].z);
        __half2 h3 = __floats2half2_rn(A[ii].w, Bv[ii].w);
        const unsigned int w0 = *reinterpret_cast<unsigned int*>(&h0);
        const unsigned int w1 = *reinterpret_cast<unsigned int*>(&h1);
        const unsigned int w2 = *reinterpret_cast<unsigned int*>(&h2);
        const unsigned int w3 = *reinterpret_cast<unsigned int*>(&h3);
        *reinterpret_cast<uint4*>(&lt[i][lane * 4]) = make_uint4(w0, w1, w2, w3);
    }
    __syncthreads();

    // ---- write phase: thread t = pixel px; one full 128-B line of T ----
    unsigned int wreg[32];
    #pragma unroll
    for (int i = 0; i < 32; ++i) wreg[i] = lt[i][t];

    const int h = 2 * hh + (t >> 7);
    const int w = t & 127;
    __half* dst = T + ((size_t)(b * H_ + h) * W_ + w) * CIN_ + cg * 64;
    uint4* d4 = reinterpret_cast<uint4*>(dst);
    #pragma unroll
    for (int j = 0; j < 8; ++j)
        d4[j] = make_uint4(wreg[4 * j], wreg[4 * j + 1], wreg[4 * j + 2], wreg[4 * j + 3]);
}

// =====================================================================
// K_B: 16 points per block, 512 threads (8 waves), 256 blocks.
// Inline prep (columns from T, dots, softmax, sites) + coalesced corner
// gather + register-blocked matvec.
// =====================================================================
__global__ __launch_bounds__(512) void kb_kernel(
    const __half* __restrict__ T,
    const float* __restrict__ ax,      // [B, NPTS]
    const float* __restrict__ ay,
    const float* __restrict__ Wp,      // [COUT, CIN] fp32
    const float* __restrict__ bp,      // [COUT]
    const float* __restrict__ Woff,    // [K, 2, CIN]
    const float* __restrict__ boff,    // [K, 2]
    const float* __restrict__ Ww,      // [K, CIN]
    const float* __restrict__ bw,      // [K]
    float* __restrict__ out)           // [4096, COUT]
{
    __shared__ float xcol[16][264];        // point columns (for dots)
    __shared__ float xsh[16][260];         // gathered X
    __shared__ float wtile[32 * 256];      // Wp chunk, 32 KB
    __shared__ float dotv[16][12];
    __shared__ float swts[16][16];
    __shared__ int   ssites[16][16];
    __shared__ float swsum[16];
    __shared__ int   spix[16], spiy[16];

    const int blk = blockIdx.x;            // 0..255
    const int p0g = blk << 4;              // first global point
    const int b   = p0g >> 9;              // / NPTS_
    const int tid = threadIdx.x;

    if (tid < 16) {
        const int gid = p0g + tid;
        spix[tid] = (int)truncf(ax[gid]);
        spiy[tid] = (int)truncf(ay[gid]);
    }
    __syncthreads();

    // ---- phase 1: point columns from T (contiguous 512 B per point) ----
    {
        const int p  = tid >> 5;           // 0..15
        const int c8 = (tid & 31) << 3;    // 0..248
        const size_t px = (size_t)(b * H_ + spiy[p]) * W_ + spix[p];
        const uint4 raw = *reinterpret_cast<const uint4*>(T + px * CIN_ + c8);
        const __half* hv = reinterpret_cast<const __half*>(&raw);
        #pragma unroll
        for (int j = 0; j < 8; ++j) xcol[p][c8 + j] = __half2float(hv[j]);
    }
    __syncthreads();

    // ---- phase 2: 192 dots (16 points x 12), 24 per wave ----
    const int wv   = tid >> 6;
    const int lane = tid & 63;
    for (int r = 0; r < 24; ++r) {
        const int idx = wv * 24 + r;       // 0..191
        const int p = idx / 12;
        const int d = idx % 12;
        const float* __restrict__ row = (d < 8) ? (Woff + d * CIN_) : (Ww + (d - 8) * CIN_);
        float s = 0.f;
        #pragma unroll
        for (int q = 0; q < 4; ++q) {
            const int c = lane + q * 64;
            s = fmaf(xcol[p][c], row[c], s);
        }
        #pragma unroll
        for (int off = 32; off > 0; off >>= 1)
            s += __shfl_down(s, off);
        if (lane == 0) dotv[p][d] = s;
    }
    __syncthreads();

    // ---- phase 3: (p,k) site weights + addresses ----
    if (tid < 64) {
        const int p = tid >> 2, k = tid & 3;
        const float l0 = dotv[p][8]  + bw[0];
        const float l1 = dotv[p][9]  + bw[1];
        const float l2 = dotv[p][10] + bw[2];
        const float l3 = dotv[p][11] + bw[3];
        const float mx = fmaxf(fmaxf(l0, l1), fmaxf(l2, l3));
        const float e0 = expf(l0 - mx), e1 = expf(l1 - mx);
        const float e2 = expf(l2 - mx), e3 = expf(l3 - mx);
        const float ek = (k == 0) ? e0 : (k == 1) ? e1 : (k == 2) ? e2 : e3;
        const float wk = ek / (e0 + e1 + e2 + e3);

        const float scale = 128.0f / 127.0f;
        const float fx = dotv[p][2 * k]     + boff[2 * k];
        const float fy = dotv[p][2 * k + 1] + boff[2 * k + 1];
        const float sxv = ((float)spix[p] + fx) * scale - 0.5f;
        const float syv = ((float)spiy[p] + fy) * scale - 0.5f;
        const float x0f = floorf(sxv), y0f = floorf(syv);
        const float wx1 = sxv - x0f, wy1 = syv - y0f;
        const int x0 = (int)x0f, y0 = (int)y0f;
        #pragma unroll
        for (int ci = 0; ci < 4; ++ci) {
            const int xi = x0 + (ci & 1);
            const int yi = y0 + (ci >> 1);
            const bool valid = (xi >= 0) & (xi < W_) & (yi >= 0) & (yi < H_);
            float wc = ((ci & 1) ? wx1 : 1.f - wx1) * ((ci >> 1) ? wy1 : 1.f - wy1) * wk;
            wc = valid ? wc : 0.f;
            const int xc = min(max(xi, 0), W_ - 1);
            const int yc = min(max(yi, 0), H_ - 1);
            swts[p][k * 4 + ci]   = wc;
            ssites[p][k * 4 + ci] = ((b * H_ + yc) * W_ + xc) * CIN_;
        }
    }
    __syncthreads();

    if (tid < 16) {
        float s = 0.f;
        #pragma unroll
        for (int i = 0; i < 16; ++i) s += swts[tid][i];
        swsum[tid] = s;    // readers cross the post-gather barrier below
    }

    // ---- phase 4: gather 16 sites per point (coalesced) ----
    {
        const int p   = tid >> 5;          // 0..15
        const int oct = tid & 31;          // 0..31
        const int c0  = oct << 3;
        float a[8] = {0.f, 0.f, 0.f, 0.f, 0.f, 0.f, 0.f, 0.f};
        #pragma unroll
        for (int s = 0; s < 16; ++s) {
            const float w = swts[p][s];
            const uint4 raw = *reinterpret_cast<const uint4*>(T + (size_t)ssites[p][s] + c0);
            const __half* hv = reinterpret_cast<const __half*>(&raw);
            #pragma unroll
            for (int j = 0; j < 8; ++j)
                a[j] = fmaf(w, __half2float(hv[j]), a[j]);
        }
        *reinterpret_cast<float4*>(&xsh[p][c0])     = make_float4(a[0], a[1], a[2], a[3]);
        *reinterpret_cast<float4*>(&xsh[p][c0 + 4]) = make_float4(a[4], a[5], a[6], a[7]);
    }
    __syncthreads();

    // ---- phase 5: matvec, thread owns 2 points x 4 outputs ----
    const int oq = tid & 63;
    const int pp = tid >> 6;
    const int o0 = oq << 2;
    const int p0 = pp << 1;

    const float4 bpv = *reinterpret_cast<const float4*>(bp + o0);
    const float ws0 = swsum[p0], ws1 = swsum[p0 + 1];
    float a00 = bpv.x * ws0, a01 = bpv.y * ws0, a02 = bpv.z * ws0, a03 = bpv.w * ws0;
    float a10 = bpv.x * ws1, a11 = bpv.y * ws1, a12 = bpv.z * ws1, a13 = bpv.w * ws1;

    for (int ch = 0; ch < 8; ++ch) {
        #pragma unroll
        for (int r = 0; r < 4; ++r) {
            const int idx = r * 512 + tid;     // 0..2047
            const int c4  = idx & 7;
            const int o   = idx >> 3;
            const float4 v = *reinterpret_cast<const float4*>(Wp + (size_t)o * CIN_ + ch * 32 + c4 * 4);
            const float vv[4] = {v.x, v.y, v.z, v.w};
            #pragma unroll
            for (int m = 0; m < 4; ++m) {
                const int c  = c4 * 4 + m;
                const int os = (o >> 2) ^ (c & 7);
                wtile[c * 256 + (os << 2) + (o & 3)] = vv[m];
            }
        }
        __syncthreads();

        const int cb = ch * 32;
        #pragma unroll
        for (int cq = 0; cq < 8; ++cq) {
            const float4 x0 = *reinterpret_cast<const float4*>(&xsh[p0][cb + (cq << 2)]);
            const float4 x1 = *reinterpret_cast<const float4*>(&xsh[p0 + 1][cb + (cq << 2)]);
            const float x0a[4] = {x0.x, x0.y, x0.z, x0.w};
            const float x1a[4] = {x1.x, x1.y, x1.z, x1.w};
            #pragma unroll
            for (int m = 0; m < 4; ++m) {
                const int c = (cq << 2) + m;
                const float4 wvv = *reinterpret_cast<const float4*>(
                    &wtile[c * 256 + ((oq ^ (c & 7)) << 2)]);
                const float xm0 = x0a[m], xm1 = x1a[m];
                a00 = fmaf(xm0, wvv.x, a00); a01 = fmaf(xm0, wvv.y, a01);
                a02 = fmaf(xm0, wvv.z, a02); a03 = fmaf(xm0, wvv.w, a03);
                a10 = fmaf(xm1, wvv.x, a10); a11 = fmaf(xm1, wvv.y, a11);
                a12 = fmaf(xm1, wvv.z, a12); a13 = fmaf(xm1, wvv.w, a13);
            }
        }
        __syncthreads();
    }

    float* o_row0 = out + (size_t)(p0g + p0) * COUT_ + o0;
    float* o_row1 = out + (size_t)(p0g + p0 + 1) * COUT_ + o0;
    *reinterpret_cast<float4*>(o_row0) = make_float4(a00, a01, a02, a03);
    *reinterpret_cast<float4*>(o_row1) = make_float4(a10, a11, a12, a13);
}

// =====================================================================
// Fallback (round-1 kernel): used only if ws_size is too small.
// =====================================================================
__global__ __launch_bounds__(256) void ple_point_kernel(
    const float* __restrict__ input, const float* __restrict__ ax,
    const float* __restrict__ ay, const float* __restrict__ Wp,
    const float* __restrict__ bp, const float* __restrict__ Woff,
    const float* __restrict__ boff, const float* __restrict__ Ww,
    const float* __restrict__ bw, float* __restrict__ out)
{
    const int gid = blockIdx.x;
    const int b   = gid >> 9;
    const int tid = threadIdx.x;

    __shared__ float xs[CIN_];
    __shared__ float dotv[12];

    const int ix = (int)truncf(ax[gid]);
    const int iy = (int)truncf(ay[gid]);
    const float* __restrict__ chan = input + (size_t)b * (CIN_ * H_ * W_) + (size_t)tid * (H_ * W_);

    xs[tid] = chan[iy * W_ + ix];
    __syncthreads();

    const int wave = tid >> 6;
    const int lane = tid & 63;
    #pragma unroll
    for (int r = 0; r < 3; ++r) {
        const int d = wave * 3 + r;
        const float* __restrict__ row = (d < 8) ? (Woff + d * CIN_) : (Ww + (d - 8) * CIN_);
        float s = 0.f;
        #pragma unroll
        for (int q = 0; q < 4; ++q) s = fmaf(xs[lane + q * 64], row[lane + q * 64], s);
        #pragma unroll
        for (int off = 32; off > 0; off >>= 1) s += __shfl_down(s, off);
        if (lane == 0) dotv[d] = s;
    }
    __syncthreads();

    float lg[K_];
    float mx = -1e30f;
    #pragma unroll
    for (int k = 0; k < K_; ++k) { lg[k] = dotv[8 + k] + bw[k]; mx = fmaxf(mx, lg[k]); }
    float se = 0.f;
    #pragma unroll
    for (int k = 0; k < K_; ++k) { lg[k] = expf(lg[k] - mx); se += lg[k]; }
    const float inv_se = 1.f / se;
    const float scale = 128.0f / 127.0f;

    float xacc = 0.f, wsum = 0.f;
    #pragma unroll
    for (int k = 0; k < K_; ++k) {
        const float wk = lg[k] * inv_se;
        const float fx = dotv[2 * k] + boff[2 * k];
        const float fy = dotv[2 * k + 1] + boff[2 * k + 1];
        const float sxv = ((float)ix + fx) * scale - 0.5f;
        const float syv = ((float)iy + fy) * scale - 0.5f;
        const float x0f = floorf(sxv), y0f = floorf(syv);
        const float wx1 = sxv - x0f, wy1 = syv - y0f;
        const int x0 = (int)x0f, y0 = (int)y0f;
        const int x1 = x0 + 1, y1 = y0 + 1;
        const float w00 = (1.f - wx1) * (1.f - wy1) * wk;
        const float w10 = wx1 * (1.f - wy1) * wk;
        const float w01 = (1.f - wx1) * wy1 * wk;
        const float w11 = wx1 * wy1 * wk;
        const bool vx0 = (x0 >= 0) && (x0 < W_);
        const bool vx1 = (x1 >= 0) && (x1 < W_);
        if (y0 >= 0 && y0 < H_) {
            const float* rowp = chan + y0 * W_;
            if (vx0) { xacc = fmaf(w00, rowp[x0], xacc); wsum += w00; }
            if (vx1) { xacc = fmaf(w10, rowp[x1], xacc); wsum += w10; }
        }
        if (y1 >= 0 && y1 < H_) {
            const float* rowp = chan + y1 * W_;
            if (vx0) { xacc = fmaf(w01, rowp[x0], xacc); wsum += w01; }
            if (vx1) { xacc = fmaf(w11, rowp[x1], xacc); wsum += w11; }
        }
    }

    xs[tid] = xacc;
    __syncthreads();

    const float* __restrict__ wrow = Wp + tid * CIN_;
    float a0 = bp[tid] * wsum, a1 = 0.f, a2 = 0.f, a3 = 0.f;
    #pragma unroll 4
    for (int c = 0; c < CIN_; c += 4) {
        const float4 wvv = *reinterpret_cast<const float4*>(wrow + c);
        a0 = fmaf(wvv.x, xs[c], a0);
        a1 = fmaf(wvv.y, xs[c + 1], a1);
        a2 = fmaf(wvv.z, xs[c + 2], a2);
        a3 = fmaf(wvv.w, xs[c + 3], a3);
    }
    out[(size_t)gid * COUT_ + tid] = (a0 + a1) + (a2 + a3);
}

extern "C" void kernel_launch(void* const* d_in, const int* in_sizes, int n_in,
                              void* d_out, int out_size, void* d_ws, size_t ws_size,
                              hipStream_t stream) {
    const float* input = (const float*)d_in[0];
    const float* ax    = (const float*)d_in[1];
    const float* ay    = (const float*)d_in[2];
    const float* Wp    = (const float*)d_in[3];
    const float* bp    = (const float*)d_in[4];
    const float* Woff  = (const float*)d_in[5];
    const float* boff  = (const float*)d_in[6];
    const float* Ww    = (const float*)d_in[7];
    const float* bw    = (const float*)d_in[8];
    float* out = (float*)d_out;

    if (ws_size >= T_BYTES_) {
        __half* T = (__half*)d_ws;
        ka_kernel<<<dim3(B_ * 4 * (H_ / 2)), dim3(256), 0, stream>>>(input, T);
        kb_kernel<<<dim3(NPTS_TOT_ / 16), dim3(512), 0, stream>>>(
            T, ax, ay, Wp, bp, Woff, boff, Ww, bw, out);
    } else {
        ple_point_kernel<<<dim3(B_ * NPTS_), dim3(256), 0, stream>>>(
            input, ax, ay, Wp, bp, Woff, boff, Ww, bw, out);
    }
}